// Round 9
// baseline (270.934 us; speedup 1.0000x reference)
//
#include <hip/hip_runtime.h>

#define NB 32
#define CCH 64
#define HH 96
#define WWID 96
#define HWP (HH*WWID)   // 9216
#define K7 448

// ws layout (float offsets):
//   t2p : [32][32][64][64] partials        = 4,194,304 floats
//   t5  : [32][64][64]                     =   131,072
//   T8t : [32][64][448] bf16 (kk-major-k') =   458,752 floats of space
//   t6  : [32][9216]                       =   294,912
//   t9  : [32][64]                         =     2,048
#define OFF_T5 4194304
#define OFF_T8 4325376
#define OFF_T6 4784128
#define OFF_T9 5079040

typedef __attribute__((ext_vector_type(8))) short short8;
typedef __attribute__((ext_vector_type(4))) short shortx4;
typedef __attribute__((ext_vector_type(4))) float floatx4;
typedef float __attribute__((ext_vector_type(4), aligned(4))) float4u;  // 4B-aligned vec load

__device__ __forceinline__ short f2bf(float x) {
    unsigned u = __float_as_uint(x);
    unsigned r = (u + 0x7FFF + ((u >> 16) & 1)) >> 16;  // RNE
    return (short)r;
}

// ---------------------------------------------------------------------------
// Kernel A (MFMA): t2 partials. t2[n,c,d] = sum_i x[n,c,i]*t1[n,d,i] (K split 32)
// ---------------------------------------------------------------------------
__device__ __forceinline__ void ld_ab(const float* __restrict__ xa, int base,
                                      float4u* va, float4u* vb, int t) {
#pragma unroll
    for (int i = 0; i < 2; i++) {
        int idx = i * 256 + t;            // [0,512)
        int c = idx >> 3, k4 = idx & 7;   // channel, k-group
        int gi = base + k4 * 4;           // multiple of 4, never crosses a row
        const float* xc = xa + c * HWP;
        va[i] = *(const float4u*)(xc + gi);
        int h = gi / WWID, w = gi - h * WWID;     // w in {0,4,...,92}
        int hr = (h == 0) ? (HH - 1) : (h - 1);
        const float* xrow = xc + hr * WWID;
        if (w < 92) {
            vb[i] = *(const float4u*)(xrow + w + 1);
        } else {  // w==92: rolled elems are 93,94,95, then wrap to 0
            float4u tmp;
            tmp.x = xrow[93]; tmp.y = xrow[94]; tmp.z = xrow[95]; tmp.w = xrow[0];
            vb[i] = tmp;
        }
    }
}

__global__ __launch_bounds__(256) void k_t2(const float* __restrict__ x,
                                            float* __restrict__ t2p) {
    int blk = blockIdx.x;
    int n = blk >> 5, sl = blk & 31;
    int k0 = sl * 288;                       // 3 full rows per slice
    __shared__ short ash[2][64][40];         // [buf][c][k] bf16, row padded 32->40
    __shared__ short bsh[2][64][40];
    int t = threadIdx.x;
    int lane = t & 63, wv = t >> 6;
    int q = lane >> 4, r16 = lane & 15;
    const float* xa = x + (size_t)n * CCH * HWP;

    floatx4 acc[4] = {};                     // 4 m-tiles x (n-tile = wv)

    float4u va[2][2], vb[2][2];
    ld_ab(xa, k0,      va[0], vb[0], t);
    ld_ab(xa, k0 + 32, va[1], vb[1], t);

#pragma unroll
    for (int it = 0; it < 9; it++) {
        const int cur = it & 1;              // compile-time under full unroll
#pragma unroll
        for (int i = 0; i < 2; i++) {
            int idx = i * 256 + t;
            int c = idx >> 3, k4 = idx & 7;
            shortx4 pa = {f2bf(va[cur][i].x), f2bf(va[cur][i].y),
                          f2bf(va[cur][i].z), f2bf(va[cur][i].w)};
            shortx4 pb = {f2bf(vb[cur][i].x), f2bf(vb[cur][i].y),
                          f2bf(vb[cur][i].z), f2bf(vb[cur][i].w)};
            *(shortx4*)&ash[cur][c][k4 * 4] = pa;
            *(shortx4*)&bsh[cur][c][k4 * 4] = pb;
        }
        if (it + 2 < 9)                      // refill the reg slot just drained
            ld_ab(xa, k0 + (it + 2) * 32, va[cur], vb[cur], t);
        __syncthreads();
        short8 bfrag = *(const short8*)&bsh[cur][wv * 16 + r16][q * 8];
#pragma unroll
        for (int mi = 0; mi < 4; mi++) {
            short8 afrag = *(const short8*)&ash[cur][mi * 16 + r16][q * 8];
            acc[mi] = __builtin_amdgcn_mfma_f32_16x16x32_bf16(afrag, bfrag, acc[mi], 0, 0, 0);
        }
    }

    // D layout: col = lane&15 (d), row = q*4+i (c within m-tile)
    float* o = t2p + (size_t)(n * 32 + sl) * 4096;
#pragma unroll
    for (int mi = 0; mi < 4; mi++) {
        int m = mi * 16 + q * 4;
#pragma unroll
        for (int i = 0; i < 4; i++)
            o[(m + i) * 64 + wv * 16 + r16] = acc[mi][i];
    }
}

// ---------------------------------------------------------------------------
// Kernel B1: t5[n,b,c] = p5[b,c] * (sum of 32 slices of t2p) / 96
// ---------------------------------------------------------------------------
__global__ __launch_bounds__(256) void k_t5(const float* __restrict__ t2p,
                                            const float* __restrict__ p5,
                                            float* __restrict__ t5) {
    int idx = blockIdx.x * 256 + threadIdx.x;
    int n = idx >> 12, rc = idx & 4095;
    float s = 0.f;
#pragma unroll
    for (int sl = 0; sl < 32; sl++)
        s += t2p[((size_t)n * 32 + sl) * 4096 + rc];
    t5[idx] = s * p5[rc] * (1.0f / 96.0f);
}

// ---------------------------------------------------------------------------
// Kernel B2: T8t[n][c][kk*64+c7] = bf16( (1/sqrt(448)) * sum_b t5[n,b,c]*p8[b,k] )
// ---------------------------------------------------------------------------
__global__ __launch_bounds__(256) void k_t8(const float* __restrict__ t5,
                                            const float* __restrict__ p8,
                                            short* __restrict__ t8t) {
    int n = blockIdx.y;
    int idx = blockIdx.x * 256 + threadIdx.x;   // [0, 448*64)
    int k = idx >> 6, c = idx & 63;
    const float* t5n = t5 + (size_t)n * 4096;
    float s = 0.f;
#pragma unroll 8
    for (int b = 0; b < 64; b++)
        s += t5n[b * 64 + c] * p8[b * K7 + k];
    int c7 = k / 7, kk = k - c7 * 7;
    t8t[((size_t)n * 64 + c) * K7 + kk * 64 + c7] = f2bf(s * 0.04724555912f);
}

// ---------------------------------------------------------------------------
// Kernel C1: t6[n,h,w] = sum_c p6[c] * dwconv3x3_d2(t1)[n,c,h,w]
// ---------------------------------------------------------------------------
__global__ __launch_bounds__(256) void k_t6(const float* __restrict__ x,
                                            const float* __restrict__ w4,
                                            const float* __restrict__ p6,
                                            float* __restrict__ t6) {
    int n = blockIdx.y;
    int pix = blockIdx.x * 256 + threadIdx.x;   // < 9216 (36*256)
    int h = pix / WWID, w = pix - h * WWID;

    int off9[9];
    float m9[9];
#pragma unroll
    for (int i = 0; i < 3; i++) {
        int gh = h + (i - 1) * 2;
        bool vr = (gh >= 0) && (gh < HH);
        int srow = vr ? ((gh + HH - 1) % HH) * WWID : 0;
        float rm = vr ? 1.f : 0.f;
#pragma unroll
        for (int j = 0; j < 3; j++) {
            int gw = w + (j - 1) * 2;
            bool vc = (gw >= 0) && (gw < WWID);
            int scol = vc ? (gw + 1) % WWID : 0;
            off9[i * 3 + j] = srow + scol;
            m9[i * 3 + j] = vc ? rm : 0.f;
        }
    }
    const float* xn = x + (size_t)n * CCH * HWP;
    float acc = 0.f;
    for (int c = 0; c < CCH; c++) {
        const float* xc = xn + c * HWP;
        float pw = p6[c];
        const float* wc = w4 + c * 9;
#pragma unroll
        for (int ij = 0; ij < 9; ij++) {
            float wm = wc[ij] * pw * m9[ij];
            acc = fmaf(wm, xc[off9[ij]], acc);
        }
    }
    t6[(size_t)n * HWP + pix] = acc;
}

// ---------------------------------------------------------------------------
// Kernel C2: t9[n,c] = (1/96) * <conv5x5(t1[c]), t6[n]>
// ---------------------------------------------------------------------------
__global__ __launch_bounds__(256) void k_t9(const float* __restrict__ x,
                                            const float* __restrict__ w3,
                                            const float* __restrict__ t6,
                                            float* __restrict__ t9) {
    int n = blockIdx.y, c = blockIdx.x;
    __shared__ float xl[100][100];
    __shared__ float red[4];
    int t = threadIdx.x;
    const float* xc = x + ((size_t)n * CCH + c) * HWP;
    const float* t6n = t6 + (size_t)n * HWP;

    // zero borders: rows 0,1,98,99 full (400) + cols 0,1,98,99 of rows 2..97 (384)
    for (int idx = t; idx < 784; idx += 256) {
        if (idx < 400) {
            int r = idx / 100, col = idx - r * 100;
            int row = r < 2 ? r : r + 96;
            xl[row][col] = 0.f;
        } else {
            int rem = idx - 400;
            int h2 = rem >> 2, c4 = rem & 3;
            int col = c4 < 2 ? c4 : c4 + 96;
            xl[2 + h2][col] = 0.f;
        }
    }
    // interior: xl[h+2][w+2] = t1[h][w] = x[(h-1)%96][(w+1)%96]
    for (int idx = t; idx < HWP; idx += 256) {
        int h = idx / WWID, w = idx - h * WWID;
        int sh = (h == 0) ? (HH - 1) : (h - 1);
        int sw = (w == WWID - 1) ? 0 : (w + 1);
        xl[h + 2][w + 2] = xc[sh * WWID + sw];
    }
    float wv[25];
#pragma unroll
    for (int i = 0; i < 25; i++) wv[i] = w3[c * 25 + i];
    __syncthreads();

    float acc = 0.f;
#pragma unroll
    for (int g = 0; g < 9; g++) {
        int idx = g * 256 + t;          // < 2304
        int h = idx / 24, wg = idx - h * 24;
        int w0 = wg * 4;
        float4 tv = *(const float4*)(t6n + h * WWID + w0);
        float conv[4] = {0.f, 0.f, 0.f, 0.f};
#pragma unroll
        for (int kh = 0; kh < 5; kh++) {
            float4 ra = *(const float4*)&xl[h + kh][w0];
            float4 rb = *(const float4*)&xl[h + kh][w0 + 4];
            float r[8] = {ra.x, ra.y, ra.z, ra.w, rb.x, rb.y, rb.z, rb.w};
#pragma unroll
            for (int kw = 0; kw < 5; kw++) {
                float wk = wv[kh * 5 + kw];
                conv[0] = fmaf(wk, r[kw],     conv[0]);
                conv[1] = fmaf(wk, r[kw + 1], conv[1]);
                conv[2] = fmaf(wk, r[kw + 2], conv[2]);
                conv[3] = fmaf(wk, r[kw + 3], conv[3]);
            }
        }
        acc = fmaf(conv[0], tv.x, acc);
        acc = fmaf(conv[1], tv.y, acc);
        acc = fmaf(conv[2], tv.z, acc);
        acc = fmaf(conv[3], tv.w, acc);
    }
#pragma unroll
    for (int off = 32; off > 0; off >>= 1) acc += __shfl_down(acc, off, 64);
    if ((t & 63) == 0) red[t >> 6] = acc;
    __syncthreads();
    if (t == 0)
        t9[n * 64 + c] = (red[0] + red[1] + red[2] + red[3]) * (1.0f / 96.0f);
}

// ---------------------------------------------------------------------------
// Kernel D: bf16 MFMA GEMM, 3 h-pairs per block, double-buffered LDS pipeline.
// out[n,c,s] = t9[n,c] + sum_{k'} T8t[n][c][k'] * T7[k'][s],  k' = kk*64+c7
// Per pair: LDS 193 rows x 64 shorts, swizzle pos = c7 ^ ((R&7)<<3), row 192 =
// zero row. Pipeline: load pair p+1 -> regs || compute pair p || store p ||
// ds_write p+1 -> other buffer; ONE barrier per pair (writes never target the
// buffer being read; reuse of a buffer is ordered by the intervening barrier).
// Grid 16x32 = 512 blocks (2/CU, LDS 49.4 KB dbuf); A and t9 amortized x3.
// ---------------------------------------------------------------------------
__global__ __launch_bounds__(256) void k_out(const float* __restrict__ x,
                                             const short* __restrict__ t8t,
                                             const float* __restrict__ t9,
                                             float* __restrict__ out) {
    int n = blockIdx.y;
    int hg = blockIdx.x;                 // h-group: pairs 3*hg .. 3*hg+2
    __shared__ short xsh[2][193 * 64];
    int t = threadIdx.x;

    // zero row 192 of both buffers
    if (t < 32) {
        ((int*)xsh[0])[192 * 32 + t] = 0;
        ((int*)xsh[1])[192 * 32 + t] = 0;
    }

    const float* xn = x + (size_t)n * CCH * HWP;
    int lane = t & 63, wv = t >> 6;
    int q = lane >> 4, sl = lane & 15;
    int mh = wv & 1;        // m-half: c tiles {mh*2, mh*2+1}
    int sh2 = wv >> 1;      // row within each h-pair
    int rbase = sh2 * 96 - 6;
    const short* Abase = t8t + (size_t)n * 64 * K7 + (mh * 32 + sl) * K7 + q * 8;

    // hoist t9 epilogue values (reused for all 3 pairs)
    float tvv[2][4];
#pragma unroll
    for (int mi = 0; mi < 2; mi++)
#pragma unroll
        for (int i = 0; i < 4; i++)
            tvv[mi][i] = t9[n * 64 + (mh * 2 + mi) * 16 + q * 4 + i];

    float pf[12][4];   // in-flight staging registers (static idx under unroll)

    // ---- initial stage: pair 0 ----
#pragma unroll
    for (int i = 0; i < 12; i++) {
        int idx = i * 256 + t;
        int r = idx / 1536;
        int rem = idx - r * 1536;
        int c7g = rem / 96, w = rem - c7g * 96;
        const float* src = xn + (size_t)(c7g * 4) * HWP + (hg * 6 + r) * WWID + w;
        pf[i][0] = src[0]; pf[i][1] = src[HWP];
        pf[i][2] = src[2 * HWP]; pf[i][3] = src[3 * HWP];
    }
#pragma unroll
    for (int i = 0; i < 12; i++) {
        int idx = i * 256 + t;
        int r = idx / 1536;
        int rem = idx - r * 1536;
        int c7g = rem / 96, w = rem - c7g * 96;
        int R = r * 96 + w;
        shortx4 pk = {f2bf(pf[i][0]), f2bf(pf[i][1]), f2bf(pf[i][2]), f2bf(pf[i][3])};
        *(shortx4*)&xsh[0][R * 64 + ((c7g * 4) ^ ((R & 7) << 3))] = pk;
    }
    __syncthreads();

#pragma unroll
    for (int p = 0; p < 3; p++) {
        // ---- issue next pair's global loads (latency hides under compute) ----
        if (p < 2) {
#pragma unroll
            for (int i = 0; i < 12; i++) {
                int idx = i * 256 + t;
                int r = idx / 1536;
                int rem = idx - r * 1536;
                int c7g = rem / 96, w = rem - c7g * 96;
                const float* src = xn + (size_t)(c7g * 4) * HWP
                                      + (hg * 6 + (p + 1) * 2 + r) * WWID + w;
                pf[i][0] = src[0]; pf[i][1] = src[HWP];
                pf[i][2] = src[2 * HWP]; pf[i][3] = src[3 * HWP];
            }
        }

        // ---- compute pair p from xsh[p&1] ----
        const short* Bb = xsh[p & 1];
        floatx4 acc[2][6] = {};
        for (int kc = 0; kc < K7; kc += 32) {
            int kk = kc >> 6;
            int c7b = (kc & 63) + q * 8;
            int iwb = sl + 2 * kk;
            short8 a[2], b[6];
#pragma unroll
            for (int mi = 0; mi < 2; mi++)
                a[mi] = *(const short8*)(Abase + mi * 16 * K7 + kc);
#pragma unroll
            for (int sj = 0; sj < 6; sj++) {
                int iw = sj * 16 + iwb;
                int Rv;
                if (sj == 0)      Rv = (iw >= 6)  ? (rbase + iw) : 192;  // left halo
                else if (sj == 5) Rv = (iw < 102) ? (rbase + iw) : 192;  // right halo
                else              Rv = rbase + iw;                       // interior
                b[sj] = *(const short8*)&Bb[Rv * 64 + (c7b ^ ((Rv & 7) << 3))];
            }
#pragma unroll
            for (int mi = 0; mi < 2; mi++)
#pragma unroll
                for (int sj = 0; sj < 6; sj++)
                    acc[mi][sj] = __builtin_amdgcn_mfma_f32_16x16x32_bf16(
                        a[mi], b[sj], acc[mi][sj], 0, 0, 0);
        }

        // ---- store pair p ----
        int h0p = hg * 6 + p * 2;
#pragma unroll
        for (int mi = 0; mi < 2; mi++) {
#pragma unroll
            for (int i = 0; i < 4; i++) {
                int c = (mh * 2 + mi) * 16 + q * 4 + i;
                float* orow = out + ((size_t)n * CCH + c) * HWP + (h0p + sh2) * WWID;
#pragma unroll
                for (int sj = 0; sj < 6; sj++)
                    orow[sj * 16 + sl] = acc[mi][sj][i] + tvv[mi][i];
            }
        }

        // ---- write next pair into the other buffer, then barrier ----
        if (p < 2) {
#pragma unroll
            for (int i = 0; i < 12; i++) {
                int idx = i * 256 + t;
                int r = idx / 1536;
                int rem = idx - r * 1536;
                int c7g = rem / 96, w = rem - c7g * 96;
                int R = r * 96 + w;
                shortx4 pk = {f2bf(pf[i][0]), f2bf(pf[i][1]),
                              f2bf(pf[i][2]), f2bf(pf[i][3])};
                *(shortx4*)&xsh[(p + 1) & 1][R * 64 + ((c7g * 4) ^ ((R & 7) << 3))] = pk;
            }
            __syncthreads();
        }
    }
}

// ---------------------------------------------------------------------------
extern "C" void kernel_launch(void* const* d_in, const int* in_sizes, int n_in,
                              void* d_out, int out_size, void* d_ws, size_t ws_size,
                              hipStream_t stream) {
    const float* x  = (const float*)d_in[0];
    const float* w3 = (const float*)d_in[1];
    const float* w4 = (const float*)d_in[2];
    const float* p5 = (const float*)d_in[3];
    const float* p6 = (const float*)d_in[4];
    const float* p8 = (const float*)d_in[5];
    float* out = (float*)d_out;
    float* ws  = (float*)d_ws;

    float* t2p = ws;
    float* t5  = ws + OFF_T5;
    short* t8t = (short*)(ws + OFF_T8);
    float* t6  = ws + OFF_T6;
    float* t9  = ws + OFF_T9;

    k_t2<<<1024, 256, 0, stream>>>(x, t2p);
    k_t5<<<512, 256, 0, stream>>>(t2p, p5, t5);
    k_t8<<<dim3(112, 32), 256, 0, stream>>>(t5, p8, t8t);
    k_t6<<<dim3(36, 32), 256, 0, stream>>>(x, w4, p6, t6);
    k_t9<<<dim3(64, 32), 256, 0, stream>>>(x, w3, t6, t9);
    k_out<<<dim3(16, 32), 256, 0, stream>>>(x, t8t, t9, out);
}

// Round 10
// 260.684 us; speedup vs baseline: 1.0393x; 1.0393x over previous
//
#include <hip/hip_runtime.h>

#define NB 32
#define CCH 64
#define HH 96
#define WWID 96
#define HWP (HH*WWID)   // 9216
#define K7 448

// ws layout (float offsets):
//   t2p : [32][32][64][64] partials        = 4,194,304 floats
//   t5  : [32][64][64]                     =   131,072
//   T8t : [32][64][448] bf16 (kk-major-k') =   458,752 floats of space
//   t6  : [32][9216]                       =   294,912
//   t9  : [32][64]                         =     2,048
#define OFF_T5 4194304
#define OFF_T8 4325376
#define OFF_T6 4784128
#define OFF_T9 5079040

typedef __attribute__((ext_vector_type(8))) short short8;
typedef __attribute__((ext_vector_type(4))) short shortx4;
typedef __attribute__((ext_vector_type(4))) float floatx4;
typedef float __attribute__((ext_vector_type(4), aligned(4))) float4u;  // 4B-aligned vec load

__device__ __forceinline__ short f2bf(float x) {
    unsigned u = __float_as_uint(x);
    unsigned r = (u + 0x7FFF + ((u >> 16) & 1)) >> 16;  // RNE
    return (short)r;
}

__device__ __forceinline__ void ld_ab(const float* __restrict__ xa, int base,
                                      float4u* va, float4u* vb, int t) {
#pragma unroll
    for (int i = 0; i < 2; i++) {
        int idx = i * 256 + t;            // [0,512)
        int c = idx >> 3, k4 = idx & 7;   // channel, k-group
        int gi = base + k4 * 4;           // multiple of 4, never crosses a row
        const float* xc = xa + c * HWP;
        va[i] = *(const float4u*)(xc + gi);
        int h = gi / WWID, w = gi - h * WWID;     // w in {0,4,...,92}
        int hr = (h == 0) ? (HH - 1) : (h - 1);
        const float* xrow = xc + hr * WWID;
        if (w < 92) {
            vb[i] = *(const float4u*)(xrow + w + 1);
        } else {  // w==92: rolled elems are 93,94,95, then wrap to 0
            float4u tmp;
            tmp.x = xrow[93]; tmp.y = xrow[94]; tmp.z = xrow[95]; tmp.w = xrow[0];
            vb[i] = tmp;
        }
    }
}

// ---------------------------------------------------------------------------
// Fused kernel 1: blocks [0,1024) = t2 partials (MFMA/LDS-bound);
//                 blocks [1024,2176) = t6 (L2-latency-bound).
// Independent (both read only x) -> heterogeneous co-residency on each CU.
// LDS: t2 path uses 20480 B (union buffer); t6 path none.
// ---------------------------------------------------------------------------
__global__ __launch_bounds__(256) void k_f1(const float* __restrict__ x,
                                            const float* __restrict__ w4,
                                            const float* __restrict__ p6,
                                            float* __restrict__ t2p,
                                            float* __restrict__ t6) {
    __shared__ short smem[2 * 64 * 40 * 2];   // 20480 B
    int bx = blockIdx.x;
    int t = threadIdx.x;

    if (bx < 1024) {
        // ---- t2: t2[n,c,d] = sum_i x[n,c,i]*t1[n,d,i], K split 32 ----
        short (*ash)[64][40] = (short(*)[64][40])smem;
        short (*bsh)[64][40] = (short(*)[64][40])(smem + 2 * 64 * 40);
        int n = bx >> 5, sl = bx & 31;
        int k0 = sl * 288;                   // 3 full rows per slice
        int lane = t & 63, wv = t >> 6;
        int q = lane >> 4, r16 = lane & 15;
        const float* xa = x + (size_t)n * CCH * HWP;

        floatx4 acc[4] = {};
        float4u va[2][2], vb[2][2];
        ld_ab(xa, k0,      va[0], vb[0], t);
        ld_ab(xa, k0 + 32, va[1], vb[1], t);

#pragma unroll
        for (int it = 0; it < 9; it++) {
            const int cur = it & 1;          // compile-time under full unroll
#pragma unroll
            for (int i = 0; i < 2; i++) {
                int idx = i * 256 + t;
                int c = idx >> 3, k4 = idx & 7;
                shortx4 pa = {f2bf(va[cur][i].x), f2bf(va[cur][i].y),
                              f2bf(va[cur][i].z), f2bf(va[cur][i].w)};
                shortx4 pb = {f2bf(vb[cur][i].x), f2bf(vb[cur][i].y),
                              f2bf(vb[cur][i].z), f2bf(vb[cur][i].w)};
                *(shortx4*)&ash[cur][c][k4 * 4] = pa;
                *(shortx4*)&bsh[cur][c][k4 * 4] = pb;
            }
            if (it + 2 < 9)
                ld_ab(xa, k0 + (it + 2) * 32, va[cur], vb[cur], t);
            __syncthreads();
            short8 bfrag = *(const short8*)&bsh[cur][wv * 16 + r16][q * 8];
#pragma unroll
            for (int mi = 0; mi < 4; mi++) {
                short8 afrag = *(const short8*)&ash[cur][mi * 16 + r16][q * 8];
                acc[mi] = __builtin_amdgcn_mfma_f32_16x16x32_bf16(afrag, bfrag, acc[mi], 0, 0, 0);
            }
        }
        float* o = t2p + (size_t)(n * 32 + sl) * 4096;
#pragma unroll
        for (int mi = 0; mi < 4; mi++) {
            int m = mi * 16 + q * 4;
#pragma unroll
            for (int i = 0; i < 4; i++)
                o[(m + i) * 64 + wv * 16 + r16] = acc[mi][i];
        }
    } else {
        // ---- t6: t6[n,h,w] = sum_c p6[c]*dwconv3x3_d2(t1)[n,c,h,w] ----
        int idx6 = bx - 1024;
        int n = idx6 / 36, pb = idx6 - n * 36;
        int pix = pb * 256 + t;              // < 9216
        int h = pix / WWID, w = pix - h * WWID;

        int off9[9];
        float m9[9];
#pragma unroll
        for (int i = 0; i < 3; i++) {
            int gh = h + (i - 1) * 2;
            bool vr = (gh >= 0) && (gh < HH);
            int srow = vr ? ((gh + HH - 1) % HH) * WWID : 0;
            float rm = vr ? 1.f : 0.f;
#pragma unroll
            for (int j = 0; j < 3; j++) {
                int gw = w + (j - 1) * 2;
                bool vc = (gw >= 0) && (gw < WWID);
                int scol = vc ? (gw + 1) % WWID : 0;
                off9[i * 3 + j] = srow + scol;
                m9[i * 3 + j] = vc ? rm : 0.f;
            }
        }
        const float* xn = x + (size_t)n * CCH * HWP;
        float acc = 0.f;
        for (int c = 0; c < CCH; c++) {
            const float* xc = xn + c * HWP;
            float pw = p6[c];
            const float* wc = w4 + c * 9;
#pragma unroll
            for (int ij = 0; ij < 9; ij++) {
                float wm = wc[ij] * pw * m9[ij];
                acc = fmaf(wm, xc[off9[ij]], acc);
            }
        }
        t6[(size_t)n * HWP + pix] = acc;
    }
}

// ---------------------------------------------------------------------------
// Fused kernel 2: blocks [0,512) = t5 (tiny reduce); [512,2560) = t9 (conv+dot).
// Both inputs (t2p, t6) complete after k_f1. LDS union: t9's 40 KB dominates.
// ---------------------------------------------------------------------------
__global__ __launch_bounds__(256) void k_f2(const float* __restrict__ t2p,
                                            const float* __restrict__ p5,
                                            float* __restrict__ t5,
                                            const float* __restrict__ x,
                                            const float* __restrict__ w3,
                                            const float* __restrict__ t6,
                                            float* __restrict__ t9) {
    __shared__ float smf[100 * 100 + 4];
    int bx = blockIdx.x;
    int t = threadIdx.x;

    if (bx < 512) {
        // ---- t5[n,b,c] = p5[b,c] * (sum of 32 slices of t2p) / 96 ----
        int idx = bx * 256 + t;
        int n = idx >> 12, rc = idx & 4095;
        float s = 0.f;
#pragma unroll
        for (int sl = 0; sl < 32; sl++)
            s += t2p[((size_t)n * 32 + sl) * 4096 + rc];
        t5[idx] = s * p5[rc] * (1.0f / 96.0f);
    } else {
        // ---- t9[n,c] = (1/96) * <conv5x5(t1[c]), t6[n]> ----
        int idx9 = bx - 512;
        int n = idx9 >> 6, c = idx9 & 63;
        float (*xl)[100] = (float(*)[100])smf;
        float* red = smf + 10000;
        const float* xc = x + ((size_t)n * CCH + c) * HWP;
        const float* t6n = t6 + (size_t)n * HWP;

        for (int idx = t; idx < 784; idx += 256) {
            if (idx < 400) {
                int r = idx / 100, col = idx - r * 100;
                int row = r < 2 ? r : r + 96;
                xl[row][col] = 0.f;
            } else {
                int rem = idx - 400;
                int h2 = rem >> 2, c4 = rem & 3;
                int col = c4 < 2 ? c4 : c4 + 96;
                xl[2 + h2][col] = 0.f;
            }
        }
        for (int idx = t; idx < HWP; idx += 256) {
            int h = idx / WWID, w = idx - h * WWID;
            int sh = (h == 0) ? (HH - 1) : (h - 1);
            int sw = (w == WWID - 1) ? 0 : (w + 1);
            xl[h + 2][w + 2] = xc[sh * WWID + sw];
        }
        float wv[25];
#pragma unroll
        for (int i = 0; i < 25; i++) wv[i] = w3[c * 25 + i];
        __syncthreads();

        float acc = 0.f;
#pragma unroll
        for (int g = 0; g < 9; g++) {
            int idx = g * 256 + t;          // < 2304
            int h = idx / 24, wg = idx - h * 24;
            int w0 = wg * 4;
            float4 tv = *(const float4*)(t6n + h * WWID + w0);
            float conv[4] = {0.f, 0.f, 0.f, 0.f};
#pragma unroll
            for (int kh = 0; kh < 5; kh++) {
                float4 ra = *(const float4*)&xl[h + kh][w0];
                float4 rb = *(const float4*)&xl[h + kh][w0 + 4];
                float r[8] = {ra.x, ra.y, ra.z, ra.w, rb.x, rb.y, rb.z, rb.w};
#pragma unroll
                for (int kw = 0; kw < 5; kw++) {
                    float wk = wv[kh * 5 + kw];
                    conv[0] = fmaf(wk, r[kw],     conv[0]);
                    conv[1] = fmaf(wk, r[kw + 1], conv[1]);
                    conv[2] = fmaf(wk, r[kw + 2], conv[2]);
                    conv[3] = fmaf(wk, r[kw + 3], conv[3]);
                }
            }
            acc = fmaf(conv[0], tv.x, acc);
            acc = fmaf(conv[1], tv.y, acc);
            acc = fmaf(conv[2], tv.z, acc);
            acc = fmaf(conv[3], tv.w, acc);
        }
#pragma unroll
        for (int off = 32; off > 0; off >>= 1) acc += __shfl_down(acc, off, 64);
        if ((t & 63) == 0) red[t >> 6] = acc;
        __syncthreads();
        if (t == 0)
            t9[n * 64 + c] = (red[0] + red[1] + red[2] + red[3]) * (1.0f / 96.0f);
    }
}

// ---------------------------------------------------------------------------
// Kernel B2: T8t[n][c][kk*64+c7] = bf16( (1/sqrt(448)) * sum_b t5[n,b,c]*p8[b,k] )
// ---------------------------------------------------------------------------
__global__ __launch_bounds__(256) void k_t8(const float* __restrict__ t5,
                                            const float* __restrict__ p8,
                                            short* __restrict__ t8t) {
    int n = blockIdx.y;
    int idx = blockIdx.x * 256 + threadIdx.x;   // [0, 448*64)
    int k = idx >> 6, c = idx & 63;
    const float* t5n = t5 + (size_t)n * 4096;
    float s = 0.f;
#pragma unroll 8
    for (int b = 0; b < 64; b++)
        s += t5n[b * 64 + c] * p8[b * K7 + k];
    int c7 = k / 7, kk = k - c7 * 7;
    t8t[((size_t)n * 64 + c) * K7 + kk * 64 + c7] = f2bf(s * 0.04724555912f);
}

// ---------------------------------------------------------------------------
// Kernel D: bf16 MFMA GEMM (round-7 structure — best measured, 46.5 us).
// LDS: 193 rows x 64 shorts, swizzle pos = c7 ^ ((R&7)<<3); row 192 = zero row.
// Two-stage A-prefetch (named a0/a1, static idx).
// ---------------------------------------------------------------------------
__global__ __launch_bounds__(256) void k_out(const float* __restrict__ x,
                                             const short* __restrict__ t8t,
                                             const float* __restrict__ t9,
                                             float* __restrict__ out) {
    int n = blockIdx.y;
    int h0 = blockIdx.x * 2;
    __shared__ short xsh[193 * 64];
    int t = threadIdx.x;

    if (t < 32) ((int*)xsh)[192 * 32 + t] = 0;

    const float* xn = x + (size_t)n * CCH * HWP;
#pragma unroll
    for (int i = 0; i < 12; i++) {
        int idx = i * 256 + t;              // [0, 3072)
        int r = idx / 1536;
        int rem = idx - r * 1536;
        int c7g = rem / 96, w = rem - c7g * 96;
        const float* src = xn + (size_t)(c7g * 4) * HWP + (h0 + r) * WWID + w;
        shortx4 p = {f2bf(src[0]), f2bf(src[HWP]), f2bf(src[2 * HWP]), f2bf(src[3 * HWP])};
        int R = r * 96 + w;
        *(shortx4*)&xsh[R * 64 + ((c7g * 4) ^ ((R & 7) << 3))] = p;
    }
    __syncthreads();

    int lane = t & 63, wv = t >> 6;
    int q = lane >> 4, sl = lane & 15;
    int mh = wv & 1;
    int sh2 = wv >> 1;
    int rbase = sh2 * 96 - 6;
    floatx4 acc[2][6] = {};
    const short* Abase = t8t + (size_t)n * 64 * K7 + (mh * 32 + sl) * K7 + q * 8;

    auto computeB = [&](int kc, const short8* a) {
        int kk = kc >> 6;
        int c7b = (kc & 63) + q * 8;
        int iwb = sl + 2 * kk;
        short8 b[6];
#pragma unroll
        for (int sj = 0; sj < 6; sj++) {
            int iw = sj * 16 + iwb;
            int Rv;
            if (sj == 0)      Rv = (iw >= 6)  ? (rbase + iw) : 192;
            else if (sj == 5) Rv = (iw < 102) ? (rbase + iw) : 192;
            else              Rv = rbase + iw;
            b[sj] = *(const short8*)&xsh[Rv * 64 + (c7b ^ ((Rv & 7) << 3))];
        }
#pragma unroll
        for (int mi = 0; mi < 2; mi++)
#pragma unroll
            for (int sj = 0; sj < 6; sj++)
                acc[mi][sj] = __builtin_amdgcn_mfma_f32_16x16x32_bf16(
                    a[mi], b[sj], acc[mi][sj], 0, 0, 0);
    };

    short8 a0[2], a1[2];
    a0[0] = *(const short8*)(Abase);
    a0[1] = *(const short8*)(Abase + 16 * K7);

    for (int kc = 0; kc < K7; kc += 64) {
        a1[0] = *(const short8*)(Abase + kc + 32);
        a1[1] = *(const short8*)(Abase + 16 * K7 + kc + 32);
        computeB(kc, a0);
        if (kc + 64 < K7) {
            a0[0] = *(const short8*)(Abase + kc + 64);
            a0[1] = *(const short8*)(Abase + 16 * K7 + kc + 64);
        }
        computeB(kc + 32, a1);
    }

    const float* t9n = t9 + n * 64;
#pragma unroll
    for (int mi = 0; mi < 2; mi++) {
#pragma unroll
        for (int i = 0; i < 4; i++) {
            int c = (mh * 2 + mi) * 16 + q * 4 + i;
            float tv = t9n[c];
            float* orow = out + ((size_t)n * CCH + c) * HWP + (h0 + sh2) * WWID;
#pragma unroll
            for (int sj = 0; sj < 6; sj++)
                orow[sj * 16 + sl] = acc[mi][sj][i] + tv;
        }
    }
}

// ---------------------------------------------------------------------------
extern "C" void kernel_launch(void* const* d_in, const int* in_sizes, int n_in,
                              void* d_out, int out_size, void* d_ws, size_t ws_size,
                              hipStream_t stream) {
    const float* x  = (const float*)d_in[0];
    const float* w3 = (const float*)d_in[1];
    const float* w4 = (const float*)d_in[2];
    const float* p5 = (const float*)d_in[3];
    const float* p6 = (const float*)d_in[4];
    const float* p8 = (const float*)d_in[5];
    float* out = (float*)d_out;
    float* ws  = (float*)d_ws;

    float* t2p = ws;
    float* t5  = ws + OFF_T5;
    short* t8t = (short*)(ws + OFF_T8);
    float* t6  = ws + OFF_T6;
    float* t9  = ws + OFF_T9;

    k_f1<<<2176, 256, 0, stream>>>(x, w4, p6, t2p, t6);
    k_f2<<<2560, 256, 0, stream>>>(t2p, p5, t5, x, w3, t6, t9);
    k_t8<<<dim3(112, 32), 256, 0, stream>>>(t5, p8, t8t);
    k_out<<<dim3(48, 32), 256, 0, stream>>>(x, t8t, t9, out);
}